// Round 7
// baseline (4974.014 us; speedup 1.0000x reference)
//
#include <hip/hip_runtime.h>
#include <hip/hip_fp16.h>

#define TT 2048
#define BB 64
#define HH 128

typedef _Float16 f16x8 __attribute__((ext_vector_type(8)));
typedef float f32x4 __attribute__((ext_vector_type(4)));

__device__ __forceinline__ float sigm(float x) {
    return __builtin_amdgcn_rcpf(1.0f + __expf(-x));
}
__device__ __forceinline__ float tanh_f(float x) {
    return 1.0f - 2.0f * __builtin_amdgcn_rcpf(1.0f + __expf(2.0f * x));
}
// LDS-only barrier: no vmcnt drain (HIP __syncthreads drains all global ops).
__device__ __forceinline__ void bar_lds() {
    asm volatile("s_waitcnt lgkmcnt(0)\n\ts_barrier" ::: "memory");
}

__device__ __forceinline__ f16x8 load_frag(const float* rowp, int kt, int lh) {
    const float4* p4 = (const float4*)(rowp + kt * 32 + lh * 8);
    float4 a = p4[0], b = p4[1];
    f16x8 f;
    f[0] = (_Float16)a.x; f[1] = (_Float16)a.y; f[2] = (_Float16)a.z; f[3] = (_Float16)a.w;
    f[4] = (_Float16)b.x; f[5] = (_Float16)b.y; f[6] = (_Float16)b.z; f[7] = (_Float16)b.w;
    return f;
}

// Fully fused 2-layer LSTM, 1 batch/block, 64 blocks, 512 thr (8 waves).
// Interval i: L0 computes h0[i], L1 computes h1[i-1]. av (h0[i-1], masked
// ds_read on lanes c==0) feeds BOTH L0's hh-matvec (Bf) and L1's ih-proj (Bi).
// Register budget is the whole game: launch_bounds(512,1) -> 2 waves/SIMD ->
// 256 unified VGPR+AGPR per wave. Frags 192 + av 16 + acc1 16 + acc0 + scalars
// ~= 250. (512,2) in round 6 capped at 128 -> weight spill to scratch
// (FETCH 17MB/WRITE 28MB signature) -> 3.7 ms.
__global__ __launch_bounds__(512, 1) void k_fused(
    const float* __restrict__ x, const int* __restrict__ lengths,
    const float* __restrict__ ff_w, const float* __restrict__ ff_b,
    const float* __restrict__ W_ih0, const float* __restrict__ W_hh0,
    const float* __restrict__ b0, const float* __restrict__ W_ih1,
    const float* __restrict__ W_hh1, const float* __restrict__ b1,
    float* __restrict__ pooled) {
    const int b = blockIdx.x;
    const int tid = threadIdx.x;
    const int w = tid >> 6;
    const int lane = tid & 63;
    const int c = lane & 15;
    const int lh = lane >> 4;
    const int un = 16 * w + c;
    __shared__ float xs[TT];
    __shared__ _Float16 Hb0[2][HH];
    __shared__ _Float16 Hb1[2][HH];

    for (int i = tid; i < TT; i += 512) xs[i] = x[b * TT + i];
    if (tid < 2 * HH) {
        ((_Float16*)Hb0)[tid] = (_Float16)0.f;
        ((_Float16*)Hb1)[tid] = (_Float16)0.f;
    }

    f16x8 Bf[4][4], Bi[4][4], Bh[4][4];
    float v[4], u0[4], bia[4];
#pragma unroll
    for (int t2 = 0; t2 < 4; ++t2) {
        const int r = t2 * HH + un;
#pragma unroll
        for (int kt = 0; kt < 4; ++kt) {
            Bf[t2][kt] = load_frag(W_hh0 + r * HH, kt, lh);
            Bi[t2][kt] = load_frag(W_ih1 + r * HH, kt, lh);
            Bh[t2][kt] = load_frag(W_hh1 + r * HH, kt, lh);
        }
        const float4* wi4 = (const float4*)(W_ih0 + r * HH);
        const float4* fw4 = (const float4*)ff_w;
        const float4* fb4 = (const float4*)ff_b;
        float vv = 0.f, uu = 0.f;
#pragma unroll
        for (int m = 0; m < HH / 4; ++m) {
            float4 a = wi4[m], fw = fw4[m], fb = fb4[m];
            vv += a.x * fw.x + a.y * fw.y + a.z * fw.z + a.w * fw.w;
            uu += a.x * fb.x + a.y * fb.y + a.z * fb.z + a.w * fb.w;
        }
        v[t2] = vv;
        u0[t2] = uu + b0[r];
        bia[t2] = b1[r];
    }
    float cst0 = 0.f, cst1 = 0.f, mean = 0.f, mx = -1e30f, last = 0.f;
    const int len = lengths[b];
    const bool ard = (c == 0);     // A-fragment reader lanes {0,16,32,48}
    const bool wr16 = (lane < 16); // real-row (m=0) lanes
    f16x8 av[4];
#pragma unroll
    for (int kt = 0; kt < 4; ++kt) av[kt] = (f16x8){0, 0, 0, 0, 0, 0, 0, 0};
    __syncthreads();

    // interval 0 (peel): L0 step 0 from zero state
    {
        const float xt = xs[0];
        float gi = sigm(xt * v[0] + u0[0]), gf = sigm(xt * v[1] + u0[1]);
        float gg = tanh_f(xt * v[2] + u0[2]), go = sigm(xt * v[3] + u0[3]);
        cst0 = gi * gg;
        float h0n = go * tanh_f(cst0);
        if (wr16) Hb0[1][un] = (_Float16)h0n;
        bar_lds();
    }

    // intervals i = 1..len: L0 step i (garbage past len-1, harmless; xs
    // clamped), L1 step i-1 (always real). rb = i&1.
    for (int i = 1; i <= len; ++i) {
        const int rb = i & 1;
        // av <- h0[i-1]
        if (ard) {
#pragma unroll
            for (int kt = 0; kt < 4; ++kt)
                av[kt] = *(const f16x8*)&Hb0[rb][kt * 32 + lh * 8];
        }
        const int xi = (i < len) ? i : (len - 1);
        const float xt = xs[xi];
        // L1 gate acc: bias + Bi.h0[i-1]  (independent 4-deep chains per t2)
        f32x4 acc1[4];
#pragma unroll
        for (int t2 = 0; t2 < 4; ++t2) {
            float ci = bia[t2];
            acc1[t2][0] = ci; acc1[t2][1] = ci; acc1[t2][2] = ci; acc1[t2][3] = ci;
        }
#pragma unroll
        for (int t2 = 0; t2 < 4; ++t2) {
#pragma unroll
            for (int kt = 0; kt < 4; ++kt)
                acc1[t2] = __builtin_amdgcn_mfma_f32_16x16x32_f16(
                    av[kt], Bi[t2][kt], acc1[t2], 0, 0, 0);
        }
        // L0 gates: x-proj + Bf.h0[i-1]; acc0 extracted per t2 (short-lived)
        float p[4];
#pragma unroll
        for (int t2 = 0; t2 < 4; ++t2) {
            float ci = xt * v[t2] + u0[t2];
            f32x4 a0;
            a0[0] = ci; a0[1] = ci; a0[2] = ci; a0[3] = ci;
#pragma unroll
            for (int kt = 0; kt < 4; ++kt)
                a0 = __builtin_amdgcn_mfma_f32_16x16x32_f16(
                    av[kt], Bf[t2][kt], a0, 0, 0, 0);
            p[t2] = a0[0];
        }
        // L0 activations + h0 publish
        {
            float gi = sigm(p[0]), gf = sigm(p[1]), gg = tanh_f(p[2]), go = sigm(p[3]);
            cst0 = gf * cst0 + gi * gg;
            float h0n = go * tanh_f(cst0);
            if (wr16) Hb0[rb ^ 1][un] = (_Float16)h0n;
        }
        // av <- h1[i-2]; Bh into acc1
        if (ard) {
#pragma unroll
            for (int kt = 0; kt < 4; ++kt)
                av[kt] = *(const f16x8*)&Hb1[rb][kt * 32 + lh * 8];
        }
#pragma unroll
        for (int t2 = 0; t2 < 4; ++t2) {
#pragma unroll
            for (int kt = 0; kt < 4; ++kt)
                acc1[t2] = __builtin_amdgcn_mfma_f32_16x16x32_f16(
                    av[kt], Bh[t2][kt], acc1[t2], 0, 0, 0);
        }
        // L1 activations + h1 publish + pooling
        {
            float gi = sigm(acc1[0][0]), gf = sigm(acc1[1][0]);
            float gg = tanh_f(acc1[2][0]), go = sigm(acc1[3][0]);
            cst1 = gf * cst1 + gi * gg;
            float h1n = go * tanh_f(cst1);
            if (wr16) Hb1[rb ^ 1][un] = (_Float16)h1n;
            mean += h1n;
            mx = fmaxf(mx, h1n);
            if (i == len) last = h1n;
        }
        bar_lds();
    }

    if (wr16) {
        pooled[b * 384 + un] = mean / (float)len;
        pooled[b * 384 + 128 + un] = mx;
        pooled[b * 384 + 256 + un] = last;
    }
}

// ---------------- head: [B,3H] @ [3H,C]^T + bias ----------------
__global__ __launch_bounds__(448) void k_head(
    const float* __restrict__ pooled, const float* __restrict__ lin_w,
    const float* __restrict__ lin_b, float* __restrict__ out) {
    int tid = threadIdx.x;  // 448 = 64*7
    int b = tid / 7, cc = tid % 7;
    const float* p = pooled + b * 384;
    const float* wr = lin_w + cc * 384;
    float a0 = 0.f, a1 = 0.f, a2 = 0.f, a3 = 0.f;
#pragma unroll
    for (int k = 0; k < 384; k += 4) {
        a0 += p[k + 0] * wr[k + 0];
        a1 += p[k + 1] * wr[k + 1];
        a2 += p[k + 2] * wr[k + 2];
        a3 += p[k + 3] * wr[k + 3];
    }
    out[tid] = lin_b[cc] + ((a0 + a1) + (a2 + a3));
}

extern "C" void kernel_launch(void* const* d_in, const int* in_sizes, int n_in,
                              void* d_out, int out_size, void* d_ws, size_t ws_size,
                              hipStream_t stream) {
    const float* x     = (const float*)d_in[0];
    const int*   lens  = (const int*)d_in[1];
    const float* ff_w  = (const float*)d_in[2];
    const float* ff_b  = (const float*)d_in[3];
    const float* W_ih0 = (const float*)d_in[4];
    const float* W_hh0 = (const float*)d_in[5];
    const float* b0    = (const float*)d_in[6];
    const float* W_ih1 = (const float*)d_in[7];
    const float* W_hh1 = (const float*)d_in[8];
    const float* b1    = (const float*)d_in[9];
    const float* lin_w = (const float*)d_in[10];
    const float* lin_b = (const float*)d_in[11];
    float* out = (float*)d_out;

    float* pooled = (float*)d_ws;  // [64*384] floats

    k_fused<<<dim3(BB), dim3(512), 0, stream>>>(
        x, lens, ff_w, ff_b, W_ih0, W_hh0, b0, W_ih1, W_hh1, b1, pooled);
    k_head<<<dim3(1), dim3(448), 0, stream>>>(pooled, lin_w, lin_b, out);
}

// Round 8
// 2773.592 us; speedup vs baseline: 1.7933x; 1.7933x over previous
//
#include <hip/hip_runtime.h>
#include <hip/hip_fp16.h>

#define TT 2048
#define BB 64
#define HH 128
#define GG 512  // 4H

typedef _Float16 f16x8 __attribute__((ext_vector_type(8)));
typedef float f32x4 __attribute__((ext_vector_type(4)));

__device__ __forceinline__ float sigm(float x) {
    return __builtin_amdgcn_rcpf(1.0f + __expf(-x));
}
__device__ __forceinline__ float tanh_f(float x) {
    return 1.0f - 2.0f * __builtin_amdgcn_rcpf(1.0f + __expf(2.0f * x));
}
// LDS-only barrier: no vmcnt drain.
__device__ __forceinline__ void bar_lds() {
    asm volatile("s_waitcnt lgkmcnt(0)\n\ts_barrier" ::: "memory");
}

__device__ __forceinline__ f16x8 load_frag(const float* rowp, int kt, int lh) {
    const float4* p4 = (const float4*)(rowp + kt * 32 + lh * 8);
    float4 a = p4[0], b = p4[1];
    f16x8 f;
    f[0] = (_Float16)a.x; f[1] = (_Float16)a.y; f[2] = (_Float16)a.z; f[3] = (_Float16)a.w;
    f[4] = (_Float16)b.x; f[5] = (_Float16)b.y; f[6] = (_Float16)b.z; f[7] = (_Float16)b.w;
    return f;
}

// Wave-specialized 3-stage pipeline. 1 batch/block, 64 blocks, 768 thr = 12
// waves = 3 groups of 4. Each group owns ONE matmul (128 frag VGPRs/wave, the
// spill-free footprint; rounds 6/7 proved 192/wave spills):
//   G0: h0[i]   = act(x[i]*v + u0 + W_hh0.h0[i-1])
//   G1: q1[i-1] = b1 + W_ih1.h0[i-1]             -> LDS Q1 double-buffer
//   G2: h1[i-2] = act(q1[i-2] + W_hh1.h1[i-3])   -> pooling
// One bar_lds per interval. Per-row consts (v,u0,b1) live in LDS.
// MFMA 16x16x32_f16 M=1: wave wg's tile (s,t2) covers rows r = t2*128 +
// 32*wg + 16*s + c; lanes lh==0 hold the real (m=0) output row.
__global__ __launch_bounds__(768, 3) void k_mega(
    const float* __restrict__ x, const int* __restrict__ lengths,
    const float* __restrict__ ff_w, const float* __restrict__ ff_b,
    const float* __restrict__ W_ih0, const float* __restrict__ W_hh0,
    const float* __restrict__ b0, const float* __restrict__ W_ih1,
    const float* __restrict__ W_hh1, const float* __restrict__ b1,
    float* __restrict__ pooled) {
    const int b = blockIdx.x;
    const int tid = threadIdx.x;
    const int w = tid >> 6;
    const int grp = w >> 2;   // 0: W_hh0, 1: W_ih1, 2: W_hh1
    const int wg = w & 3;     // wave-in-group
    const int lane = tid & 63;
    const int c = lane & 15;
    const int lh = lane >> 4;
    __shared__ float xs[TT];
    __shared__ _Float16 Hb0[2][HH];
    __shared__ _Float16 Hb1[2][HH];
    __shared__ float Q1[2][GG];
    __shared__ float Vb[GG], Ub[GG], Bb[GG];

    for (int i = tid; i < TT; i += 768) xs[i] = x[b * TT + i];
    if (tid < 2 * HH) {
        ((_Float16*)Hb0)[tid] = (_Float16)0.f;
        ((_Float16*)Hb1)[tid] = (_Float16)0.f;
    }
    if (tid < GG) {  // rank-1 x-projection folded per row + biases -> LDS
        const float4* wi4 = (const float4*)(W_ih0 + tid * HH);
        const float4* fw4 = (const float4*)ff_w;
        const float4* fb4 = (const float4*)ff_b;
        float vv = 0.f, uu = 0.f;
#pragma unroll
        for (int m = 0; m < HH / 4; ++m) {
            float4 a = wi4[m], fw = fw4[m], fb = fb4[m];
            vv += a.x * fw.x + a.y * fw.y + a.z * fw.z + a.w * fw.w;
            uu += a.x * fb.x + a.y * fb.y + a.z * fb.z + a.w * fb.w;
        }
        Vb[tid] = vv;
        Ub[tid] = uu + b0[tid];
        Bb[tid] = b1[tid];
    }

    const float* Wsrc = (grp == 0) ? W_hh0 : (grp == 1) ? W_ih1 : W_hh1;
    f16x8 Bw[2][4][4];  // [s][t2][kt] = 128 VGPRs
#pragma unroll
    for (int s = 0; s < 2; ++s)
#pragma unroll
        for (int t2 = 0; t2 < 4; ++t2) {
            const int r = t2 * HH + 32 * wg + 16 * s + c;
#pragma unroll
            for (int kt = 0; kt < 4; ++kt) Bw[s][t2][kt] = load_frag(Wsrc + r * HH, kt, lh);
        }

    const int len = lengths[b];
    const bool ard = (c == 0);    // A-fragment reader lanes
    const bool mrow = (lh == 0);  // real output row (m=0) lanes
    float cst0[2] = {0.f, 0.f}, cst1[2] = {0.f, 0.f};
    float mean[2] = {0.f, 0.f}, mxv[2] = {-1e30f, -1e30f}, lastv[2] = {0.f, 0.f};
    f16x8 av[4];
#pragma unroll
    for (int kt = 0; kt < 4; ++kt) av[kt] = (f16x8){0, 0, 0, 0, 0, 0, 0, 0};
    __syncthreads();

    for (int i = 0; i <= len + 1; ++i) {
        const int rb = i & 1;
        if (grp == 0) {
            if (i < len) {
                if (ard) {
#pragma unroll
                    for (int kt = 0; kt < 4; ++kt)
                        av[kt] = *(const f16x8*)&Hb0[rb ^ 1][kt * 32 + lh * 8];
                }
                const float xt = xs[i];
#pragma unroll
                for (int s = 0; s < 2; ++s) {
                    const int ub = 32 * wg + 16 * s + c;
                    float p[4];
#pragma unroll
                    for (int t2 = 0; t2 < 4; ++t2) {
                        f32x4 a = (f32x4){0.f, 0.f, 0.f, 0.f};
#pragma unroll
                        for (int kt = 0; kt < 4; ++kt)
                            a = __builtin_amdgcn_mfma_f32_16x16x32_f16(
                                av[kt], Bw[s][t2][kt], a, 0, 0, 0);
                        p[t2] = a[0] + xt * Vb[t2 * HH + ub] + Ub[t2 * HH + ub];
                    }
                    float gi = sigm(p[0]), gf = sigm(p[1]);
                    float gg = tanh_f(p[2]), go = sigm(p[3]);
                    cst0[s] = gf * cst0[s] + gi * gg;
                    float h0n = go * tanh_f(cst0[s]);
                    if (mrow) Hb0[rb][ub] = (_Float16)h0n;
                }
            }
        } else if (grp == 1) {
            if (i >= 1 && i <= len) {
                if (ard) {
#pragma unroll
                    for (int kt = 0; kt < 4; ++kt)
                        av[kt] = *(const f16x8*)&Hb0[rb ^ 1][kt * 32 + lh * 8];
                }
#pragma unroll
                for (int s = 0; s < 2; ++s) {
                    const int ub = 32 * wg + 16 * s + c;
#pragma unroll
                    for (int t2 = 0; t2 < 4; ++t2) {
                        f32x4 a = (f32x4){0.f, 0.f, 0.f, 0.f};
#pragma unroll
                        for (int kt = 0; kt < 4; ++kt)
                            a = __builtin_amdgcn_mfma_f32_16x16x32_f16(
                                av[kt], Bw[s][t2][kt], a, 0, 0, 0);
                        if (mrow) Q1[rb][t2 * HH + ub] = a[0] + Bb[t2 * HH + ub];
                    }
                }
            }
        } else {
            if (i >= 2) {
                if (ard) {
#pragma unroll
                    for (int kt = 0; kt < 4; ++kt)
                        av[kt] = *(const f16x8*)&Hb1[rb ^ 1][kt * 32 + lh * 8];
                }
#pragma unroll
                for (int s = 0; s < 2; ++s) {
                    const int ub = 32 * wg + 16 * s + c;
                    float p[4];
#pragma unroll
                    for (int t2 = 0; t2 < 4; ++t2) {
                        f32x4 a = (f32x4){0.f, 0.f, 0.f, 0.f};
#pragma unroll
                        for (int kt = 0; kt < 4; ++kt)
                            a = __builtin_amdgcn_mfma_f32_16x16x32_f16(
                                av[kt], Bw[s][t2][kt], a, 0, 0, 0);
                        p[t2] = a[0] + Q1[rb ^ 1][t2 * HH + ub];
                    }
                    float gi = sigm(p[0]), gf = sigm(p[1]);
                    float gg = tanh_f(p[2]), go = sigm(p[3]);
                    cst1[s] = gf * cst1[s] + gi * gg;
                    float h1n = go * tanh_f(cst1[s]);
                    if (mrow) Hb1[rb][ub] = (_Float16)h1n;
                    mean[s] += h1n;
                    mxv[s] = fmaxf(mxv[s], h1n);
                    if (i == len + 1) lastv[s] = h1n;
                }
            }
        }
        bar_lds();
    }

    if (grp == 2 && mrow) {
#pragma unroll
        for (int s = 0; s < 2; ++s) {
            const int ub = 32 * wg + 16 * s + c;
            pooled[b * 384 + ub] = mean[s] / (float)len;
            pooled[b * 384 + 128 + ub] = mxv[s];
            pooled[b * 384 + 256 + ub] = lastv[s];
        }
    }
}

// ---------------- head: [B,3H] @ [3H,C]^T + bias ----------------
__global__ __launch_bounds__(448) void k_head(
    const float* __restrict__ pooled, const float* __restrict__ lin_w,
    const float* __restrict__ lin_b, float* __restrict__ out) {
    int tid = threadIdx.x;  // 448 = 64*7
    int b = tid / 7, cc = tid % 7;
    const float* p = pooled + b * 384;
    const float* wr = lin_w + cc * 384;
    float a0 = 0.f, a1 = 0.f, a2 = 0.f, a3 = 0.f;
#pragma unroll
    for (int k = 0; k < 384; k += 4) {
        a0 += p[k + 0] * wr[k + 0];
        a1 += p[k + 1] * wr[k + 1];
        a2 += p[k + 2] * wr[k + 2];
        a3 += p[k + 3] * wr[k + 3];
    }
    out[tid] = lin_b[cc] + ((a0 + a1) + (a2 + a3));
}

extern "C" void kernel_launch(void* const* d_in, const int* in_sizes, int n_in,
                              void* d_out, int out_size, void* d_ws, size_t ws_size,
                              hipStream_t stream) {
    const float* x     = (const float*)d_in[0];
    const int*   lens  = (const int*)d_in[1];
    const float* ff_w  = (const float*)d_in[2];
    const float* ff_b  = (const float*)d_in[3];
    const float* W_ih0 = (const float*)d_in[4];
    const float* W_hh0 = (const float*)d_in[5];
    const float* b0    = (const float*)d_in[6];
    const float* W_ih1 = (const float*)d_in[7];
    const float* W_hh1 = (const float*)d_in[8];
    const float* b1    = (const float*)d_in[9];
    const float* lin_w = (const float*)d_in[10];
    const float* lin_b = (const float*)d_in[11];
    float* out = (float*)d_out;

    float* pooled = (float*)d_ws;  // [64*384] floats

    k_mega<<<dim3(BB), dim3(768), 0, stream>>>(
        x, lens, ff_w, ff_b, W_ih0, W_hh0, b0, W_ih1, W_hh1, b1, pooled);
    k_head<<<dim3(1), dim3(448), 0, stream>>>(pooled, lin_w, lin_b, out);
}

// Round 9
// 2346.872 us; speedup vs baseline: 2.1194x; 1.1818x over previous
//
#include <hip/hip_runtime.h>
#include <hip/hip_fp16.h>

#define TT 2048
#define BB 64
#define HH 128
#define GG 512  // 4H

typedef _Float16 f16x8 __attribute__((ext_vector_type(8)));
typedef float f32x4 __attribute__((ext_vector_type(4)));

__device__ __forceinline__ float sigm(float x) {
    return __builtin_amdgcn_rcpf(1.0f + __expf(-x));
}
__device__ __forceinline__ float tanh_f(float x) {
    return 1.0f - 2.0f * __builtin_amdgcn_rcpf(1.0f + __expf(2.0f * x));
}
// LDS-only barrier: no vmcnt drain.
__device__ __forceinline__ void bar_lds() {
    asm volatile("s_waitcnt lgkmcnt(0)\n\ts_barrier" ::: "memory");
}

__device__ __forceinline__ f16x8 load_frag(const float* rowp, int kt, int lh) {
    const float4* p4 = (const float4*)(rowp + kt * 32 + lh * 8);
    float4 a = p4[0], b = p4[1];
    f16x8 f;
    f[0] = (_Float16)a.x; f[1] = (_Float16)a.y; f[2] = (_Float16)a.z; f[3] = (_Float16)a.w;
    f[4] = (_Float16)b.x; f[5] = (_Float16)b.y; f[6] = (_Float16)b.z; f[7] = (_Float16)b.w;
    return f;
}

// Wave-specialized 3-stage pipeline (round-8 structure, proven correct).
// 1 batch/block, 64 blocks, 768 thr = 12 waves = 3 groups of 4:
//   G0: h0[i]   = act(x[i]*v + u0 + W_hh0.h0[i-1])
//   G1: q1[i-1] = b1 + W_ih1.h0[i-1]             -> LDS Q1 double-buffer
//   G2: h1[i-2] = act(q1[i-2] + W_hh1.h1[i-3])   -> pooling
// THE round-9 fix: amdgpu_waves_per_eu(3,3) pins BOTH min and max occupancy.
// launch_bounds' 2nd arg only sets the min; the backend's default occupancy
// heuristic still shrank VGPRs to 84 in round 8 and rematerialized the 128
// fragment VGPRs from global EVERY interval (L3 masked it in FETCH_SIZE;
// 2713 us). Budget at 3 waves/SIMD = 512/3 ~= 170 >= our ~165 need.
__global__ __attribute__((amdgpu_flat_work_group_size(768, 768),
                          amdgpu_waves_per_eu(3, 3))) void k_mega(
    const float* __restrict__ x, const int* __restrict__ lengths,
    const float* __restrict__ ff_w, const float* __restrict__ ff_b,
    const float* __restrict__ W_ih0, const float* __restrict__ W_hh0,
    const float* __restrict__ b0, const float* __restrict__ W_ih1,
    const float* __restrict__ W_hh1, const float* __restrict__ b1,
    float* __restrict__ pooled) {
    const int b = blockIdx.x;
    const int tid = threadIdx.x;
    const int w = tid >> 6;
    const int grp = w >> 2;   // 0: W_hh0, 1: W_ih1, 2: W_hh1
    const int wg = w & 3;     // wave-in-group
    const int lane = tid & 63;
    const int c = lane & 15;
    const int lh = lane >> 4;
    __shared__ float xs[TT];
    __shared__ _Float16 Hb0[2][HH];
    __shared__ _Float16 Hb1[2][HH];
    __shared__ float Q1[2][GG];
    __shared__ float Vb[GG], Ub[GG], Bb[GG];

    for (int i = tid; i < TT; i += 768) xs[i] = x[b * TT + i];
    if (tid < 2 * HH) {
        ((_Float16*)Hb0)[tid] = (_Float16)0.f;
        ((_Float16*)Hb1)[tid] = (_Float16)0.f;
    }
    if (tid < GG) {  // rank-1 x-projection folded per row + biases -> LDS
        const float4* wi4 = (const float4*)(W_ih0 + tid * HH);
        const float4* fw4 = (const float4*)ff_w;
        const float4* fb4 = (const float4*)ff_b;
        float vv = 0.f, uu = 0.f;
#pragma unroll
        for (int m = 0; m < HH / 4; ++m) {
            float4 a = wi4[m], fw = fw4[m], fb = fb4[m];
            vv += a.x * fw.x + a.y * fw.y + a.z * fw.z + a.w * fw.w;
            uu += a.x * fb.x + a.y * fb.y + a.z * fb.z + a.w * fb.w;
        }
        Vb[tid] = vv;
        Ub[tid] = uu + b0[tid];
        Bb[tid] = b1[tid];
    }

    const float* Wsrc = (grp == 0) ? W_hh0 : (grp == 1) ? W_ih1 : W_hh1;
    f16x8 Bw[2][4][4];  // [s][t2][kt] = 128 VGPRs (must stay resident!)
#pragma unroll
    for (int s = 0; s < 2; ++s)
#pragma unroll
        for (int t2 = 0; t2 < 4; ++t2) {
            const int r = t2 * HH + 32 * wg + 16 * s + c;
#pragma unroll
            for (int kt = 0; kt < 4; ++kt) Bw[s][t2][kt] = load_frag(Wsrc + r * HH, kt, lh);
        }

    const int len = lengths[b];
    const bool ard = (c == 0);    // A-fragment reader lanes
    const bool mrow = (lh == 0);  // real output row (m=0) lanes
    float cst0[2] = {0.f, 0.f}, cst1[2] = {0.f, 0.f};
    float mean[2] = {0.f, 0.f}, mxv[2] = {-1e30f, -1e30f};
    f16x8 av[4];
#pragma unroll
    for (int kt = 0; kt < 4; ++kt) av[kt] = (f16x8){0, 0, 0, 0, 0, 0, 0, 0};
    __syncthreads();

    for (int i = 0; i <= len + 1; ++i) {
        const int rb = i & 1;
        if (grp == 0) {
            if (i < len) {
                if (ard) {
#pragma unroll
                    for (int kt = 0; kt < 4; ++kt)
                        av[kt] = *(const f16x8*)&Hb0[rb ^ 1][kt * 32 + lh * 8];
                }
                const float xt = xs[i];
#pragma unroll
                for (int s = 0; s < 2; ++s) {
                    const int ub = 32 * wg + 16 * s + c;
                    float p[4];
#pragma unroll
                    for (int t2 = 0; t2 < 4; ++t2) {
                        f32x4 a = (f32x4){0.f, 0.f, 0.f, 0.f};
#pragma unroll
                        for (int kt = 0; kt < 4; ++kt)
                            a = __builtin_amdgcn_mfma_f32_16x16x32_f16(
                                av[kt], Bw[s][t2][kt], a, 0, 0, 0);
                        p[t2] = a[0] + xt * Vb[t2 * HH + ub] + Ub[t2 * HH + ub];
                    }
                    float gi = sigm(p[0]), gf = sigm(p[1]);
                    float gg = tanh_f(p[2]), go = sigm(p[3]);
                    cst0[s] = gf * cst0[s] + gi * gg;
                    float h0n = go * tanh_f(cst0[s]);
                    if (mrow) Hb0[rb][ub] = (_Float16)h0n;
                }
            }
        } else if (grp == 1) {
            if (i >= 1 && i <= len) {
                if (ard) {
#pragma unroll
                    for (int kt = 0; kt < 4; ++kt)
                        av[kt] = *(const f16x8*)&Hb0[rb ^ 1][kt * 32 + lh * 8];
                }
#pragma unroll
                for (int s = 0; s < 2; ++s) {
                    const int ub = 32 * wg + 16 * s + c;
#pragma unroll
                    for (int t2 = 0; t2 < 4; ++t2) {
                        f32x4 a = (f32x4){0.f, 0.f, 0.f, 0.f};
#pragma unroll
                        for (int kt = 0; kt < 4; ++kt)
                            a = __builtin_amdgcn_mfma_f32_16x16x32_f16(
                                av[kt], Bw[s][t2][kt], a, 0, 0, 0);
                        if (mrow) Q1[rb][t2 * HH + ub] = a[0] + Bb[t2 * HH + ub];
                    }
                }
            }
        } else {
            if (i >= 2) {
                if (ard) {
#pragma unroll
                    for (int kt = 0; kt < 4; ++kt)
                        av[kt] = *(const f16x8*)&Hb1[rb ^ 1][kt * 32 + lh * 8];
                }
#pragma unroll
                for (int s = 0; s < 2; ++s) {
                    const int ub = 32 * wg + 16 * s + c;
                    float p[4];
#pragma unroll
                    for (int t2 = 0; t2 < 4; ++t2) {
                        f32x4 a = (f32x4){0.f, 0.f, 0.f, 0.f};
#pragma unroll
                        for (int kt = 0; kt < 4; ++kt)
                            a = __builtin_amdgcn_mfma_f32_16x16x32_f16(
                                av[kt], Bw[s][t2][kt], a, 0, 0, 0);
                        p[t2] = a[0] + Q1[rb ^ 1][t2 * HH + ub];
                    }
                    float gi = sigm(p[0]), gf = sigm(p[1]);
                    float gg = tanh_f(p[2]), go = sigm(p[3]);
                    cst1[s] = gf * cst1[s] + gi * gg;
                    float h1n = go * tanh_f(cst1[s]);
                    if (mrow) Hb1[rb][ub] = (_Float16)h1n;
                    mean[s] += h1n;
                    mxv[s] = fmaxf(mxv[s], h1n);
                }
            }
        }
        bar_lds();
    }

    if (grp == 2 && mrow) {
#pragma unroll
        for (int s = 0; s < 2; ++s) {
            const int ub = 32 * wg + 16 * s + c;
            // last = h1[len-1], written to Hb1[(len+1)&1] at interval len+1.
            // One extra fp16 rounding vs keeping it in a register (~2^-11).
            pooled[b * 384 + ub] = mean[s] / (float)len;
            pooled[b * 384 + 128 + ub] = mxv[s];
            pooled[b * 384 + 256 + ub] = (float)Hb1[(len + 1) & 1][ub];
        }
    }
}

// ---------------- head: [B,3H] @ [3H,C]^T + bias ----------------
__global__ __launch_bounds__(448) void k_head(
    const float* __restrict__ pooled, const float* __restrict__ lin_w,
    const float* __restrict__ lin_b, float* __restrict__ out) {
    int tid = threadIdx.x;  // 448 = 64*7
    int b = tid / 7, cc = tid % 7;
    const float* p = pooled + b * 384;
    const float* wr = lin_w + cc * 384;
    float a0 = 0.f, a1 = 0.f, a2 = 0.f, a3 = 0.f;
#pragma unroll
    for (int k = 0; k < 384; k += 4) {
        a0 += p[k + 0] * wr[k + 0];
        a1 += p[k + 1] * wr[k + 1];
        a2 += p[k + 2] * wr[k + 2];
        a3 += p[k + 3] * wr[k + 3];
    }
    out[tid] = lin_b[cc] + ((a0 + a1) + (a2 + a3));
}

extern "C" void kernel_launch(void* const* d_in, const int* in_sizes, int n_in,
                              void* d_out, int out_size, void* d_ws, size_t ws_size,
                              hipStream_t stream) {
    const float* x     = (const float*)d_in[0];
    const int*   lens  = (const int*)d_in[1];
    const float* ff_w  = (const float*)d_in[2];
    const float* ff_b  = (const float*)d_in[3];
    const float* W_ih0 = (const float*)d_in[4];
    const float* W_hh0 = (const float*)d_in[5];
    const float* b0    = (const float*)d_in[6];
    const float* W_ih1 = (const float*)d_in[7];
    const float* W_hh1 = (const float*)d_in[8];
    const float* b1    = (const float*)d_in[9];
    const float* lin_w = (const float*)d_in[10];
    const float* lin_b = (const float*)d_in[11];
    float* out = (float*)d_out;

    float* pooled = (float*)d_ws;  // [64*384] floats

    k_mega<<<dim3(BB), dim3(768), 0, stream>>>(
        x, lens, ff_w, ff_b, W_ih0, W_hh0, b0, W_ih1, W_hh1, b1, pooled);
    k_head<<<dim3(1), dim3(448), 0, stream>>>(pooled, lin_w, lin_b, out);
}